// Round 3
// baseline (604.605 us; speedup 1.0000x reference)
//
#include <hip/hip_runtime.h>
#include <math.h>

namespace {
constexpr int Bn = 8, Cn = 256, Hn = 96, Wn = 128;
constexpr int HWn = Hn * Wn;          // 12288
constexpr int CHWn = Cn * HWn;
constexpr int Kn = 81;
constexpr int TW = 32, TH = 6;        // tile per block
constexpr int HR = TH + 8;            // 14 halo rows
constexpr int HC = TW + 8;            // 40 halo cols
constexpr int HCP = 44;               // padded LDS row stride (floats), 176B = 11*16B
constexpr int CC = 8;                 // channels per LDS chunk
constexpr int KS = 2;                 // C-split factor (occupancy 13.5 -> 27 waves/CU)
constexpr int CHALF = Cn / KS;        // 128 channels per slice
constexpr int NSUB = 8 * 9 * 6;       // 432 threads per slice
constexpr int NTHREADS = NSUB * KS;   // 864
constexpr int HALO = HR * HC;         // 560
constexpr int SCRS = 21;              // scratch stride (odd -> conflict-free combine)
}

__global__ __launch_bounds__(NTHREADS, 7)   // 7 waves/SIMD needed for 2 blocks/CU -> VGPR<=73
void corr81_kernel(const float* __restrict__ fa,
                   const float* __restrict__ fb,
                   float* __restrict__ out) {
  __shared__ __align__(16) float lfb[KS][CC][HR][HCP];  // 39424 B
  __shared__ float ssb[KS][HALO];                       //  4480 B

  const int tx = threadIdx.x;      // 0..7  column group (4 px each)
  const int g  = threadIdx.y;      // 0..8  == dy
  const int tz = threadIdx.z;      // 0..11
  const int ty = tz % 6;           // row in tile
  const int ks = tz / 6;           // C-slice
  const int stid = tx + 8 * g + 72 * ty;   // 0..431 within slice
  const int tid  = tx + 8 * (g + 9 * tz);  // 0..863

  // XCD swizzle: id%8 -> XCD; give each XCD one batch image's 64 tiles.
  const int flat = blockIdx.x;
  const int o = (flat & 7) * 64 + (flat >> 3);
  const int b  = o >> 6;
  const int r  = o & 63;
  const int h0 = (r >> 2) * TH;
  const int w0 = (r & 3) * TW;
  const int wb = w0 + 4 * tx;

  for (int i = tid; i < KS * HALO; i += NTHREADS) (&ssb[0][0])[i] = 0.0f;

  float acc[9][4];
  #pragma unroll
  for (int k = 0; k < 9; ++k) {
    #pragma unroll
    for (int j = 0; j < 4; ++j) acc[k][j] = 0.0f;
  }
  float ssa[4] = {0.f, 0.f, 0.f, 0.f};

  const float* faP = fa + (size_t)b * CHWn + (size_t)(ks * CHALF) * HWn
                   + (h0 + ty) * Wn + wb;

  // staging assignments: 560 halo px over 432 slice-threads, 2 rounds
  int   s_hr[2], s_hc[2];
  bool  s_on[2], s_ok[2];
  const float* s_ptr[2];
  #pragma unroll
  for (int i = 0; i < 2; ++i) {
    int px = stid + NSUB * i;
    s_on[i] = (px < HALO);
    int hr = px / HC, hc = px - hr * HC;
    s_hr[i] = hr; s_hc[i] = hc;
    int gh = h0 - 4 + hr, gw = w0 - 4 + hc;
    s_ok[i] = s_on[i] && gh >= 0 && gh < Hn && gw >= 0 && gw < Wn;
    s_ptr[i] = fb + (size_t)b * CHWn + (size_t)(ks * CHALF) * HWn
             + (size_t)gh * Wn + gw;
  }
  __syncthreads();

  for (int c0 = 0; c0 < CHALF; c0 += CC) {
    // ---- stage this slice's fb chunk into LDS + fb sumsq (owner-exclusive) ----
    #pragma unroll
    for (int i = 0; i < 2; ++i) {
      if (s_on[i]) {
        float ss = 0.f;
        if (s_ok[i]) {
          const float* p = s_ptr[i] + (size_t)c0 * HWn;
          #pragma unroll
          for (int cc = 0; cc < CC; ++cc) {
            float v = p[(size_t)cc * HWn];
            lfb[ks][cc][s_hr[i]][s_hc[i]] = v;
            ss += v * v;
          }
        } else {
          #pragma unroll
          for (int cc = 0; cc < CC; ++cc) lfb[ks][cc][s_hr[i]][s_hc[i]] = 0.f;
        }
        ssb[ks][s_hr[i] * HC + s_hc[i]] += ss;
      }
    }
    // fa prefetch (independent of the barrier; L1-served across g groups)
    float4 areg[CC];
    #pragma unroll
    for (int cc = 0; cc < CC; ++cc)
      areg[cc] = *(const float4*)(faP + (size_t)(c0 + cc) * HWn);
    __syncthreads();

    // ---- compute: one dy (=g), 9 dx shifts x 4 px per thread ----
    #pragma unroll
    for (int cc = 0; cc < CC; ++cc) {
      const float a0 = areg[cc].x, a1 = areg[cc].y, a2 = areg[cc].z, a3 = areg[cc].w;
      ssa[0] += a0 * a0; ssa[1] += a1 * a1; ssa[2] += a2 * a2; ssa[3] += a3 * a3;
      const float* rowp = &lfb[ks][cc][ty + g][4 * tx];
      const float4 wa = *(const float4*)(rowp);
      const float4 wv = *(const float4*)(rowp + 4);
      const float4 wc = *(const float4*)(rowp + 8);
      const float win[12] = {wa.x, wa.y, wa.z, wa.w,
                             wv.x, wv.y, wv.z, wv.w,
                             wc.x, wc.y, wc.z, wc.w};
      #pragma unroll
      for (int dx = 0; dx < 9; ++dx) {
        acc[dx][0] += a0 * win[dx + 0];
        acc[dx][1] += a1 * win[dx + 1];
        acc[dx][2] += a2 * win[dx + 2];
        acc[dx][3] += a3 * win[dx + 3];
      }
    }
    __syncthreads();
  }

  // ---- combine fb sumsq across slices -> rnorm_b in ssb[0] ----
  for (int i = tid; i < HALO; i += NTHREADS)
    ssb[0][i] = 1.0f / fmaxf(sqrtf(ssb[0][i] + ssb[1][i]), 1e-12f);
  __syncthreads();

  // ---- combine acc/ssa across slices via lfb scratch (2 phases) ----
  float* scr = &lfb[0][0][0][0];   // 9856 floats; need 432*21 = 9072
  if (ks == 1) {
    #pragma unroll
    for (int dx = 0; dx < 4; ++dx)
      #pragma unroll
      for (int j = 0; j < 4; ++j) scr[stid * SCRS + dx * 4 + j] = acc[dx][j];
    #pragma unroll
    for (int j = 0; j < 4; ++j) scr[stid * SCRS + 16 + j] = ssa[j];
  }
  __syncthreads();
  if (ks == 0) {
    #pragma unroll
    for (int dx = 0; dx < 4; ++dx)
      #pragma unroll
      for (int j = 0; j < 4; ++j) acc[dx][j] += scr[stid * SCRS + dx * 4 + j];
    #pragma unroll
    for (int j = 0; j < 4; ++j) ssa[j] += scr[stid * SCRS + 16 + j];
  }
  __syncthreads();
  if (ks == 1) {
    #pragma unroll
    for (int dx = 4; dx < 9; ++dx)
      #pragma unroll
      for (int j = 0; j < 4; ++j) scr[stid * SCRS + (dx - 4) * 4 + j] = acc[dx][j];
  }
  __syncthreads();

  if (ks == 0) {
    #pragma unroll
    for (int dx = 4; dx < 9; ++dx)
      #pragma unroll
      for (int j = 0; j < 4; ++j) acc[dx][j] += scr[stid * SCRS + (dx - 4) * 4 + j];

    float rna[4];
    #pragma unroll
    for (int j = 0; j < 4; ++j) rna[j] = 1.0f / fmaxf(sqrtf(ssa[j]), 1e-12f);

    float* outP = out + (size_t)b * (Kn * HWn) + (h0 + ty) * Wn + wb;
    const int rr = ty + g;           // halo row of fb pixel for dy=g
    #pragma unroll
    for (int dx = 0; dx < 9; ++dx) {
      const int k = g * 9 + dx;
      float4 v;
      v.x = acc[dx][0] * rna[0] * ssb[0][rr * HC + 4 * tx + dx + 0];
      v.y = acc[dx][1] * rna[1] * ssb[0][rr * HC + 4 * tx + dx + 1];
      v.z = acc[dx][2] * rna[2] * ssb[0][rr * HC + 4 * tx + dx + 2];
      v.w = acc[dx][3] * rna[3] * ssb[0][rr * HC + 4 * tx + dx + 3];
      *(float4*)(outP + (size_t)k * HWn) = v;
    }
  }
}

extern "C" void kernel_launch(void* const* d_in, const int* in_sizes, int n_in,
                              void* d_out, int out_size, void* d_ws, size_t ws_size,
                              hipStream_t stream) {
  const float* fa = (const float*)d_in[0];
  const float* fb = (const float*)d_in[1];
  float* outp = (float*)d_out;
  dim3 grid(512);         // 8 b * 16 h-tiles * 4 w-tiles -> exactly 2 blocks/CU
  dim3 block(8, 9, 12);   // 864 threads: (tx, g=dy, ty*2 C-slices)
  hipLaunchKernelGGL(corr81_kernel, grid, block, 0, stream, fa, fb, outp);
}

// Round 4
// 301.715 us; speedup vs baseline: 2.0039x; 2.0039x over previous
//
#include <hip/hip_runtime.h>
#include <math.h>

namespace {
constexpr int Bn = 8, Cn = 256, Hn = 96, Wn = 128;
constexpr int HWn = Hn * Wn;          // 12288
constexpr int CHWn = Cn * HWn;
constexpr int Kn = 81;
constexpr int TW = 32, TH = 6;        // tile per block
constexpr int HR = TH + 8;            // 14 halo rows
constexpr int HC = TW + 8;            // 40 halo cols
constexpr int HCP = 44;               // padded LDS row stride (floats), 176B = 11*16B
constexpr int CC = 8;                 // channels per LDS chunk
constexpr int KS = 2;                 // C-split factor (occupancy 13.5 -> 27 waves/CU)
constexpr int CHALF = Cn / KS;        // 128 channels per slice
constexpr int NSUB = 8 * 9 * 6;       // 432 threads per slice
constexpr int NTHREADS = NSUB * KS;   // 864
constexpr int HALO = HR * HC;         // 560
constexpr int SCRS = 21;              // scratch stride (odd -> conflict-free combine)
}

// (864,7) in R3 capped VGPR and spilled acc/areg to scratch (VGPR=36,
// WRITE_SIZE 837 MB, dur 468us). (864,4) = cap 128: let the allocator
// land naturally (~56-70); 2 blocks/CU need <=75.
__global__ __launch_bounds__(NTHREADS, 4)
void corr81_kernel(const float* __restrict__ fa,
                   const float* __restrict__ fb,
                   float* __restrict__ out) {
  __shared__ __align__(16) float lfb[KS][CC][HR][HCP];  // 39424 B
  __shared__ float ssb[KS][HALO];                       //  4480 B

  const int tx = threadIdx.x;      // 0..7  column group (4 px each)
  const int g  = threadIdx.y;      // 0..8  == dy
  const int tz = threadIdx.z;      // 0..11
  const int ty = tz % 6;           // row in tile
  const int ks = tz / 6;           // C-slice
  const int stid = tx + 8 * g + 72 * ty;   // 0..431 within slice
  const int tid  = tx + 8 * (g + 9 * tz);  // 0..863

  // XCD swizzle: id%8 -> XCD; give each XCD one batch image's 64 tiles.
  const int flat = blockIdx.x;
  const int o = (flat & 7) * 64 + (flat >> 3);
  const int b  = o >> 6;
  const int r  = o & 63;
  const int h0 = (r >> 2) * TH;
  const int w0 = (r & 3) * TW;
  const int wb = w0 + 4 * tx;

  for (int i = tid; i < KS * HALO; i += NTHREADS) (&ssb[0][0])[i] = 0.0f;

  float acc[9][4];
  #pragma unroll
  for (int k = 0; k < 9; ++k) {
    #pragma unroll
    for (int j = 0; j < 4; ++j) acc[k][j] = 0.0f;
  }
  float ssa[4] = {0.f, 0.f, 0.f, 0.f};

  const float* faP = fa + (size_t)b * CHWn + (size_t)(ks * CHALF) * HWn
                   + (h0 + ty) * Wn + wb;

  // staging assignments: 560 halo px over 432 slice-threads, 2 rounds
  int   s_hr[2], s_hc[2];
  bool  s_on[2], s_ok[2];
  const float* s_ptr[2];
  #pragma unroll
  for (int i = 0; i < 2; ++i) {
    int px = stid + NSUB * i;
    s_on[i] = (px < HALO);
    int hr = px / HC, hc = px - hr * HC;
    s_hr[i] = hr; s_hc[i] = hc;
    int gh = h0 - 4 + hr, gw = w0 - 4 + hc;
    s_ok[i] = s_on[i] && gh >= 0 && gh < Hn && gw >= 0 && gw < Wn;
    s_ptr[i] = fb + (size_t)b * CHWn + (size_t)(ks * CHALF) * HWn
             + (size_t)gh * Wn + gw;
  }
  __syncthreads();

  for (int c0 = 0; c0 < CHALF; c0 += CC) {
    // ---- stage this slice's fb chunk into LDS + fb sumsq (owner-exclusive) ----
    #pragma unroll
    for (int i = 0; i < 2; ++i) {
      if (s_on[i]) {
        float ss = 0.f;
        if (s_ok[i]) {
          const float* p = s_ptr[i] + (size_t)c0 * HWn;
          #pragma unroll
          for (int cc = 0; cc < CC; ++cc) {
            float v = p[(size_t)cc * HWn];
            lfb[ks][cc][s_hr[i]][s_hc[i]] = v;
            ss += v * v;
          }
        } else {
          #pragma unroll
          for (int cc = 0; cc < CC; ++cc) lfb[ks][cc][s_hr[i]][s_hc[i]] = 0.f;
        }
        ssb[ks][s_hr[i] * HC + s_hc[i]] += ss;
      }
    }
    // fa prefetch batch 0 only (register diet: 16 VGPRs, not 32)
    float4 areg[4];
    #pragma unroll
    for (int cc = 0; cc < 4; ++cc)
      areg[cc] = *(const float4*)(faP + (size_t)(c0 + cc) * HWn);
    __syncthreads();

    // ---- compute: one dy (=g), 9 dx shifts x 4 px per thread ----
    #pragma unroll
    for (int half = 0; half < 2; ++half) {
      if (half == 1) {
        #pragma unroll
        for (int cc = 0; cc < 4; ++cc)
          areg[cc] = *(const float4*)(faP + (size_t)(c0 + 4 + cc) * HWn);
      }
      #pragma unroll
      for (int cc = 0; cc < 4; ++cc) {
        const float a0 = areg[cc].x, a1 = areg[cc].y, a2 = areg[cc].z, a3 = areg[cc].w;
        ssa[0] += a0 * a0; ssa[1] += a1 * a1; ssa[2] += a2 * a2; ssa[3] += a3 * a3;
        const float* rowp = &lfb[ks][half * 4 + cc][ty + g][4 * tx];
        const float4 wa = *(const float4*)(rowp);
        const float4 wv = *(const float4*)(rowp + 4);
        const float4 wc = *(const float4*)(rowp + 8);
        const float win[12] = {wa.x, wa.y, wa.z, wa.w,
                               wv.x, wv.y, wv.z, wv.w,
                               wc.x, wc.y, wc.z, wc.w};
        #pragma unroll
        for (int dx = 0; dx < 9; ++dx) {
          acc[dx][0] += a0 * win[dx + 0];
          acc[dx][1] += a1 * win[dx + 1];
          acc[dx][2] += a2 * win[dx + 2];
          acc[dx][3] += a3 * win[dx + 3];
        }
      }
    }
    __syncthreads();
  }

  // ---- combine fb sumsq across slices -> rnorm_b in ssb[0] ----
  for (int i = tid; i < HALO; i += NTHREADS)
    ssb[0][i] = 1.0f / fmaxf(sqrtf(ssb[0][i] + ssb[1][i]), 1e-12f);
  __syncthreads();

  // ---- combine acc/ssa across slices via lfb scratch (2 phases) ----
  float* scr = &lfb[0][0][0][0];   // 9856 floats; need 432*21 = 9072
  if (ks == 1) {
    #pragma unroll
    for (int dx = 0; dx < 4; ++dx)
      #pragma unroll
      for (int j = 0; j < 4; ++j) scr[stid * SCRS + dx * 4 + j] = acc[dx][j];
    #pragma unroll
    for (int j = 0; j < 4; ++j) scr[stid * SCRS + 16 + j] = ssa[j];
  }
  __syncthreads();
  if (ks == 0) {
    #pragma unroll
    for (int dx = 0; dx < 4; ++dx)
      #pragma unroll
      for (int j = 0; j < 4; ++j) acc[dx][j] += scr[stid * SCRS + dx * 4 + j];
    #pragma unroll
    for (int j = 0; j < 4; ++j) ssa[j] += scr[stid * SCRS + 16 + j];
  }
  __syncthreads();
  if (ks == 1) {
    #pragma unroll
    for (int dx = 4; dx < 9; ++dx)
      #pragma unroll
      for (int j = 0; j < 4; ++j) scr[stid * SCRS + (dx - 4) * 4 + j] = acc[dx][j];
  }
  __syncthreads();

  if (ks == 0) {
    #pragma unroll
    for (int dx = 4; dx < 9; ++dx)
      #pragma unroll
      for (int j = 0; j < 4; ++j) acc[dx][j] += scr[stid * SCRS + (dx - 4) * 4 + j];

    float rna[4];
    #pragma unroll
    for (int j = 0; j < 4; ++j) rna[j] = 1.0f / fmaxf(sqrtf(ssa[j]), 1e-12f);

    float* outP = out + (size_t)b * (Kn * HWn) + (h0 + ty) * Wn + wb;
    const int rr = ty + g;           // halo row of fb pixel for dy=g
    #pragma unroll
    for (int dx = 0; dx < 9; ++dx) {
      const int k = g * 9 + dx;
      float4 v;
      v.x = acc[dx][0] * rna[0] * ssb[0][rr * HC + 4 * tx + dx + 0];
      v.y = acc[dx][1] * rna[1] * ssb[0][rr * HC + 4 * tx + dx + 1];
      v.z = acc[dx][2] * rna[2] * ssb[0][rr * HC + 4 * tx + dx + 2];
      v.w = acc[dx][3] * rna[3] * ssb[0][rr * HC + 4 * tx + dx + 3];
      *(float4*)(outP + (size_t)k * HWn) = v;
    }
  }
}

extern "C" void kernel_launch(void* const* d_in, const int* in_sizes, int n_in,
                              void* d_out, int out_size, void* d_ws, size_t ws_size,
                              hipStream_t stream) {
  const float* fa = (const float*)d_in[0];
  const float* fb = (const float*)d_in[1];
  float* outp = (float*)d_out;
  dim3 grid(512);         // 8 b * 16 h-tiles * 4 w-tiles -> exactly 2 blocks/CU
  dim3 block(8, 9, 12);   // 864 threads: (tx, g=dy, ty x 2 C-slices)
  hipLaunchKernelGGL(corr81_kernel, grid, block, 0, stream, fa, fb, outp);
}